// Round 15
// baseline (380.586 us; speedup 1.0000x reference)
//
#include <hip/hip_runtime.h>
#include <math.h>

typedef _Float16 f16;
typedef _Float16 f16x8 __attribute__((ext_vector_type(8)));
typedef _Float16 f16x4 __attribute__((ext_vector_type(4)));
typedef float f32x4v __attribute__((ext_vector_type(4)));

#define Bb 8
#define Ss 2048
#define Ee 1024
#define BSr (Bb*Ss)
#define MB 1048576ull

// ---------------------------------------------------------------- helpers
__device__ __forceinline__ void gll16(const void* gp, void* lp) {
    __builtin_amdgcn_global_load_lds(
        (const __attribute__((address_space(1))) unsigned int*)gp,
        (__attribute__((address_space(3))) unsigned int*)lp,
        16, 0, 0);
}

#define MFMA16(a, b, c) __builtin_amdgcn_mfma_f32_16x16x32_f16((a), (b), (c), 0, 0, 0)
#define SBAR() asm volatile("s_barrier" ::: "memory")

// ================================================================ prep kernels
__global__ __launch_bounds__(256)
void split_xw(const float* __restrict__ x, const float* __restrict__ Wv,
              f16* __restrict__ xh, f16* __restrict__ Wvh)
{
    const int bid = blockIdx.x;
    const float* src; f16* dst; int i;
    if (bid < 16384) { src = x;  dst = xh;  i = (bid * 256 + threadIdx.x) * 4; }
    else             { src = Wv; dst = Wvh; i = ((bid - 16384) * 256 + threadIdx.x) * 4; }
    float4 v = *(const float4*)&src[i];
    f16x4 h4;
    h4[0] = (f16)v.x; h4[1] = (f16)v.y; h4[2] = (f16)v.z; h4[3] = (f16)v.w;
    *(f16x4*)&dst[i] = h4;
}

__global__ __launch_bounds__(256)
void transpose_split(const float* __restrict__ Wq, const float* __restrict__ Wk,
                     f16* __restrict__ WqTh, f16* __restrict__ WqTl,
                     f16* __restrict__ WkTh, f16* __restrict__ WkTl)
{
    __shared__ float ts[64][65];
    const int z = blockIdx.z;
    const float* W = z ? Wk : Wq;
    f16* Th = z ? WkTh : WqTh;
    f16* Tl = z ? WkTl : WqTl;
    const int e0 = blockIdx.x * 64, j0 = blockIdx.y * 64;
    const int t = threadIdx.x;
    {
        const int jj = t >> 2, c0 = (t & 3) * 16;
        #pragma unroll
        for (int m = 0; m < 4; ++m) {
            float4 v = *(const float4*)&W[(size_t)(j0 + jj) * Ee + e0 + c0 + m * 4];
            ts[jj][c0 + m*4 + 0] = v.x; ts[jj][c0 + m*4 + 1] = v.y;
            ts[jj][c0 + m*4 + 2] = v.z; ts[jj][c0 + m*4 + 3] = v.w;
        }
    }
    __syncthreads();
    {
        const int ee = t >> 2, jc0 = (t & 3) * 16;
        f16x8 h0, h1, l0, l1;
        #pragma unroll
        for (int m = 0; m < 16; ++m) {
            float val = ts[jc0 + m][ee];
            f16 hh = (f16)val; f16 ll = (f16)(val - (float)hh);
            if (m < 8) { h0[m] = hh; l0[m] = ll; }
            else       { h1[m-8] = hh; l1[m-8] = ll; }
        }
        size_t off = (size_t)(e0 + ee) * Ee + j0 + jc0;
        *(f16x8*)&Th[off]     = h0; *(f16x8*)&Th[off + 8] = h1;
        *(f16x8*)&Tl[off]     = l0; *(f16x8*)&Tl[off + 8] = l1;
    }
}

__global__ __launch_bounds__(256)
void compute_Mt(const f16* __restrict__ WkTh, const f16* __restrict__ WkTl,
                const f16* __restrict__ WqTh, const f16* __restrict__ WqTl,
                float* __restrict__ Mpart)
{
    __shared__ f16 Ah[128][32];
    __shared__ f16 Al[128][32];
    __shared__ f16 Bh[128][32];
    __shared__ f16 Bl[128][32];

    const int bn = blockIdx.x, bm = blockIdx.y, z = blockIdx.z;
    const int t = threadIdx.x;
    const int lane = t & 63;
    const int w = t >> 6;
    const int wr = w >> 1, wc = w & 1;
    const int lr = lane & 15;
    const int kq = (lane >> 4) << 3;
    const int rS = w * 32 + (lane >> 2);
    const int eS = (lane & 3) * 8;

    const f16* gAh = WkTh + ((size_t)(bm * 128 + rS)) * Ee + z * 256 + eS;
    const f16* gAl = WkTl + ((size_t)(bm * 128 + rS)) * Ee + z * 256 + eS;
    const f16* gBh = WqTh + ((size_t)(bn * 128 + rS)) * Ee + z * 256 + eS;
    const f16* gBl = WqTl + ((size_t)(bn * 128 + rS)) * Ee + z * 256 + eS;

    f32x4v acc[4][4];
    #pragma unroll
    for (int i = 0; i < 4; ++i)
        #pragma unroll
        for (int j = 0; j < 4; ++j) acc[i][j] = (f32x4v)0.f;

    for (int k0 = 0; k0 < 256; k0 += 32) {
        __syncthreads();
        #pragma unroll
        for (int c = 0; c < 2; ++c) {
            const size_t go = (size_t)c * 16 * Ee + k0;
            const int lo = w * 1024 + c * 512;
            gll16(gAh + go, &Ah[0][0] + lo);
            gll16(gAl + go, &Al[0][0] + lo);
            gll16(gBh + go, &Bh[0][0] + lo);
            gll16(gBl + go, &Bl[0][0] + lo);
        }
        __syncthreads();

        f16x8 fah[4], fal[4], fbh[4], fbl[4];
        #pragma unroll
        for (int i = 0; i < 4; ++i) {
            fah[i] = *(const f16x8*)&Ah[wr * 64 + i * 16 + lr][kq];
            fal[i] = *(const f16x8*)&Al[wr * 64 + i * 16 + lr][kq];
            fbh[i] = *(const f16x8*)&Bh[wc * 64 + i * 16 + lr][kq];
            fbl[i] = *(const f16x8*)&Bl[wc * 64 + i * 16 + lr][kq];
        }
        #pragma unroll
        for (int i = 0; i < 4; ++i)
            #pragma unroll
            for (int j = 0; j < 4; ++j) {
                acc[i][j] = MFMA16(fah[i], fbh[j], acc[i][j]);
                acc[i][j] = MFMA16(fah[i], fbl[j], acc[i][j]);
                acc[i][j] = MFMA16(fal[i], fbh[j], acc[i][j]);
            }
    }

    #pragma unroll
    for (int i = 0; i < 4; ++i) {
        #pragma unroll
        for (int j = 0; j < 4; ++j) {
            const int col = bn * 128 + wc * 64 + j * 16 + lr;
            #pragma unroll
            for (int r = 0; r < 4; ++r) {
                const int row = bm * 128 + wr * 64 + i * 16 + (lane >> 4) * 4 + r;
                Mpart[(size_t)z * MB + (size_t)row * Ee + col] = acc[i][j][r];
            }
        }
    }
}

__global__ __launch_bounds__(256)
void reduce_Mt(const float* __restrict__ Mpart, f16* __restrict__ Mth, f16* __restrict__ Mtl)
{
    const size_t i4 = ((size_t)blockIdx.x * 256 + threadIdx.x) * 4;
    float4 a = *(const float4*)&Mpart[i4];
    float4 b = *(const float4*)&Mpart[MB + i4];
    float4 c = *(const float4*)&Mpart[2 * MB + i4];
    float4 d = *(const float4*)&Mpart[3 * MB + i4];
    float s[4] = {a.x + b.x + c.x + d.x, a.y + b.y + c.y + d.y,
                  a.z + b.z + c.z + d.z, a.w + b.w + c.w + d.w};
    f16x4 h, l;
    #pragma unroll
    for (int m = 0; m < 4; ++m) { f16 hh = (f16)s[m]; h[m] = hh; l[m] = (f16)(s[m] - (float)hh); }
    *(f16x4*)&Mth[i4] = h;
    *(f16x4*)&Mtl[i4] = l;
}

// w[f] = sum_j Wk[j,f]*bq[j]  (q'-epilogue bias; folds score's +v_b). grid 4.
__global__ __launch_bounds__(256)
void wker(const float* __restrict__ Wk, const float* __restrict__ bq,
          float* __restrict__ wbuf)
{
    const int f = blockIdx.x * 256 + threadIdx.x;
    float acc = 0.f;
    for (int j = 0; j < 1024; ++j)
        acc += Wk[(size_t)j * Ee + f] * bq[j];
    wbuf[f] = acc;
}

// ================================================================ round-12 K-loop (verified best)
template<bool DUAL>
__device__ __forceinline__ void kloop32(
    const f16* __restrict__ Ag, const int sA,
    const f16* __restrict__ Bhg, const f16* __restrict__ Blg, const int sB,
    const int NT, f16* __restrict__ lds,
    f32x4v acc[8][4], const int w, const int lane)
{
    constexpr int SETF = DUAL ? 24576 : 16384;
    const int wr = w >> 2, wc = w & 3;
    const int srcA = (w * 16 + (lane & 15)) * sA + (lane >> 4) * 8;
    const int srcB = (w * 16 + (lane & 15)) * sB + (lane >> 4) * 8;
    const int lrd = lane * 8;

#define STAGE8(t, s) do {                                                   \
        const int k0_ = (t) * 32;                                           \
        const f16* gA_ = Ag + k0_ + srcA;                                   \
        const f16* gB_ = Bhg + k0_ + srcB;                                  \
        f16* dA_ = lds + (s) * SETF + w * 512;                              \
        f16* dB_ = lds + (s) * SETF + 8192 + w * 512;                       \
        gll16(gA_,                       dA_);                              \
        gll16(gA_ + (size_t)8 * 16 * sA, dA_ + 8 * 512);                    \
        gll16(gB_,                       dB_);                              \
        gll16(gB_ + (size_t)8 * 16 * sB, dB_ + 8 * 512);                    \
        if (DUAL) {                                                         \
            const f16* gL_ = Blg + k0_ + srcB;                              \
            f16* dL_ = lds + (s) * SETF + 16384 + w * 512;                  \
            gll16(gL_,                       dL_);                          \
            gll16(gL_ + (size_t)8 * 16 * sB, dL_ + 8 * 512);                \
        }                                                                   \
    } while (0)

    STAGE8(0, 0);
    STAGE8(1, 1);
    if (DUAL) asm volatile("s_waitcnt vmcnt(6)" ::: "memory");
    else      asm volatile("s_waitcnt vmcnt(4)" ::: "memory");
    SBAR();

    for (int t = 0; t < NT; ++t) {
        const int s = t % 3;
        if (t + 2 < NT) STAGE8(t + 2, (t + 2) % 3);

        const f16* As = lds + s * SETF;
        const f16* Bh = As + 8192;
        const f16* Bl = As + 16384;
        f16x8 fa[8], fbh[4], fbl[4];
        #pragma unroll
        for (int i = 0; i < 8; ++i)
            fa[i] = *(const f16x8*)(As + (wr * 8 + i) * 512 + lrd);
        #pragma unroll
        for (int j = 0; j < 4; ++j)
            fbh[j] = *(const f16x8*)(Bh + (wc * 4 + j) * 512 + lrd);
        if (DUAL) {
            #pragma unroll
            for (int j = 0; j < 4; ++j)
                fbl[j] = *(const f16x8*)(Bl + (wc * 4 + j) * 512 + lrd);
        }
        #pragma unroll
        for (int j = 0; j < 4; ++j)
            #pragma unroll
            for (int i = 0; i < 8; ++i) {
                acc[i][j] = MFMA16(fa[i], fbh[j], acc[i][j]);
                if (DUAL)
                    acc[i][j] = MFMA16(fa[i], fbl[j], acc[i][j]);
            }

        if (t + 2 < NT) {
            if (DUAL) asm volatile("s_waitcnt vmcnt(6)" ::: "memory");
            else      asm volatile("s_waitcnt vmcnt(4)" ::: "memory");
        } else if (t + 1 < NT) {
            asm volatile("s_waitcnt vmcnt(0)" ::: "memory");
        }
        SBAR();
    }
#undef STAGE8
}

// ================================================================ proj3: q'' = xh*Mt^T + w (dual), v = xh*Wvh^T -> vT
__global__ __launch_bounds__(512, 2)
void proj3(const f16* __restrict__ xh,
           const f16* __restrict__ Mth, const f16* __restrict__ Mtl,
           const f16* __restrict__ Wvh, const float* __restrict__ bv,
           const float* __restrict__ wbuf,
           f16* __restrict__ qp, f16* __restrict__ vT)
{
    __shared__ f16 lds[73728];

    const int lin = blockIdx.x;
    const int l = (lin & 7) * 64 + (lin >> 3);
    const int zc = l & 7;
    const int by = l >> 3;
    const int z = zc >> 2;
    const int col0 = (zc & 3) * 256;
    const int row0 = by * 256;

    const int t = threadIdx.x;
    const int lane = t & 63;
    const int w = t >> 6;
    const int wr = w >> 2, wc = w & 3;

    f32x4v acc[8][4];
    #pragma unroll
    for (int i = 0; i < 8; ++i)
        #pragma unroll
        for (int j = 0; j < 4; ++j) acc[i][j] = (f32x4v)0.f;

    const f16* Ax = xh + (size_t)row0 * Ee;
    if (z == 0) {
        kloop32<true>(Ax, Ee, Mth + (size_t)col0 * Ee, Mtl + (size_t)col0 * Ee, Ee,
                      32, lds, acc, w, lane);
        #pragma unroll
        for (int i = 0; i < 8; ++i) {
            #pragma unroll
            for (int j = 0; j < 4; ++j) {
                const int col = col0 + wc * 64 + j * 16 + (lane & 15);
                const float b = wbuf[col];   // folds score's per-column +v_b
                #pragma unroll
                for (int r = 0; r < 4; ++r) {
                    const int row = row0 + wr * 128 + i * 16 + (lane >> 4) * 4 + r;
                    qp[(size_t)row * Ee + col] = (f16)(acc[i][j][r] + b);
                }
            }
        }
    } else {
        kloop32<false>(Ax, Ee, Wvh + (size_t)col0 * Ee, Wvh + (size_t)col0 * Ee, Ee,
                       32, lds, acc, w, lane);
        #pragma unroll
        for (int i = 0; i < 8; ++i) {
            #pragma unroll
            for (int j = 0; j < 4; ++j) {
                const int e = col0 + wc * 64 + j * 16 + (lane & 15);
                const float b = bv[e];
                const int srow = row0 + wr * 128 + i * 16 + (lane >> 4) * 4;
                const int bb = srow >> 11;
                const int s = srow & 2047;
                f16x4 pk;
                #pragma unroll
                for (int r = 0; r < 4; ++r) pk[r] = (f16)(acc[i][j][r] + b);
                *(f16x4*)&vT[((size_t)bb * Ee + e) * Ss + s] = pk;
            }
        }
    }
}

// ================================================================ scores: S = q'' * xh^T
__global__ __launch_bounds__(512, 2)
void score8(const f16* __restrict__ qp, const f16* __restrict__ xh,
            float* __restrict__ Sbuf, int batch0)
{
    __shared__ f16 lds[49152];

    const int lin = blockIdx.x;
    const int cpx = gridDim.x >> 3;
    const int l = (lin & 7) * cpx + (lin >> 3);
    const int bn = l & 7;
    const int bm = (l >> 3) & 7;
    const int zb = l >> 6;
    const int b = batch0 + zb;

    const int t = threadIdx.x;
    const int lane = t & 63;
    const int w = t >> 6;
    const int wr = w >> 2, wc = w & 3;

    const f16* Aq = qp + ((size_t)b * Ss + bm * 256) * Ee;
    const f16* Bk = xh + ((size_t)b * Ss + bn * 256) * Ee;

    f32x4v acc[8][4];
    #pragma unroll
    for (int i = 0; i < 8; ++i)
        #pragma unroll
        for (int j = 0; j < 4; ++j) acc[i][j] = (f32x4v)0.f;

    kloop32<false>(Aq, Ee, Bk, Bk, Ee, 32, lds, acc, w, lane);

    #pragma unroll
    for (int i = 0; i < 8; ++i) {
        #pragma unroll
        for (int j = 0; j < 4; ++j) {
            const int col = bn * 256 + wc * 64 + j * 16 + (lane & 15);
            #pragma unroll
            for (int r = 0; r < 4; ++r) {
                const int row = zb * Ss + bm * 256 + wr * 128 + i * 16 + (lane >> 4) * 4 + r;
                Sbuf[(size_t)row * 2048 + col] = acc[i][j][r];
            }
        }
    }
}

// ================================================================ row softmax
__global__ __launch_bounds__(256)
void softmax_rows(float* __restrict__ Sbuf)
{
    __shared__ float red[8];
    const int t = threadIdx.x;
    const int w = t >> 6;
    float* Srow = Sbuf + (size_t)blockIdx.x * 2048;

    float4 a = *(const float4*)&Srow[t * 8];
    float4 c = *(const float4*)&Srow[t * 8 + 4];
    float v[8] = {a.x, a.y, a.z, a.w, c.x, c.y, c.z, c.w};

    float m = v[0];
    #pragma unroll
    for (int i = 1; i < 8; ++i) m = fmaxf(m, v[i]);
    #pragma unroll
    for (int off = 1; off < 64; off <<= 1) m = fmaxf(m, __shfl_xor(m, off, 64));
    if ((t & 63) == 0) red[w] = m;
    __syncthreads();
    m = fmaxf(fmaxf(red[0], red[1]), fmaxf(red[2], red[3]));

    float e[8], s = 0.f;
    #pragma unroll
    for (int i = 0; i < 8; ++i) { e[i] = __expf(v[i] - m); s += e[i]; }
    #pragma unroll
    for (int off = 1; off < 64; off <<= 1) s += __shfl_xor(s, off, 64);
    if ((t & 63) == 0) red[4 + w] = s;
    __syncthreads();
    s = red[4] + red[5] + red[6] + red[7];

    const float inv = 1.0f / s;
    f16x8 pk;
    #pragma unroll
    for (int i = 0; i < 8; ++i) pk[i] = (f16)(e[i] * inv);
    *(f16x8*)(((f16*)Srow) + t * 8) = pk;
}

// ================================================================ pv256: O = P*v, all 8 batches. grid 256.
__global__ __launch_bounds__(512, 2)
void pv256(const float* __restrict__ Sbuf, const f16* __restrict__ vT,
           float* __restrict__ out)
{
    __shared__ f16 lds[49152];

    const int lin = blockIdx.x;
    const int l = (lin & 7) * 32 + (lin >> 3);
    const int bn = l & 3;
    const int bm = (l >> 2) & 7;
    const int b  = l >> 5;

    const int t = threadIdx.x;
    const int lane = t & 63;
    const int w = t >> 6;
    const int wr = w >> 2, wc = w & 3;

    const f16* gA = (const f16*)Sbuf + ((size_t)(b * Ss + bm * 256)) * 4096;
    const f16* gB = vT + ((size_t)b * Ee + bn * 256) * Ss;

    f32x4v acc[8][4];
    #pragma unroll
    for (int i = 0; i < 8; ++i)
        #pragma unroll
        for (int j = 0; j < 4; ++j) acc[i][j] = (f32x4v)0.f;

    kloop32<false>(gA, 4096, gB, gB, Ss, 64, lds, acc, w, lane);

    #pragma unroll
    for (int i = 0; i < 8; ++i) {
        #pragma unroll
        for (int j = 0; j < 4; ++j) {
            const int col = bn * 256 + wc * 64 + j * 16 + (lane & 15);
            #pragma unroll
            for (int r = 0; r < 4; ++r) {
                const int row = bm * 256 + wr * 128 + i * 16 + (lane >> 4) * 4 + r;
                out[((size_t)b * Ss + row) * Ee + col] = acc[i][j][r];
            }
        }
    }
}

// ================================================================ pv_gemm (128^2 fallback for nb<8)
__global__ __launch_bounds__(256)
void pv_gemm(const float* __restrict__ Sbuf, const f16* __restrict__ vT,
             float* __restrict__ out, int batch0)
{
    __shared__ f16 Pt[128][32];
    __shared__ f16 Vt[128][32];

    const int zb = blockIdx.z;
    const int b = batch0 + zb;
    const int bm = blockIdx.y;
    const int bn = blockIdx.x;

    const int t = threadIdx.x;
    const int lane = t & 63;
    const int w = t >> 6;
    const int wr = w >> 1, wc = w & 1;
    const int lr = lane & 15;
    const int kq = (lane >> 4) << 3;

    const int rS = w * 32 + (lane >> 2);
    const int eS = (lane & 3) * 8;

    const f16* Pbase = (const f16*)Sbuf;
    const f16* gA = Pbase + ((size_t)(zb * Ss + bm * 128 + rS)) * 4096 + eS;
    const f16* gB = vT + ((size_t)b * Ee + bn * 128 + rS) * Ss + eS;

    f32x4v acc[4][4];
    #pragma unroll
    for (int i = 0; i < 4; ++i)
        #pragma unroll
        for (int j = 0; j < 4; ++j) acc[i][j] = (f32x4v)0.f;

    for (int k0 = 0; k0 < Ss; k0 += 32) {
        __syncthreads();
        #pragma unroll
        for (int c = 0; c < 2; ++c) {
            const int lo = w * 1024 + c * 512;
            gll16(gA + (size_t)c * 16 * 4096 + k0, &Pt[0][0] + lo);
            gll16(gB + (size_t)c * 16 * Ss + k0,   &Vt[0][0] + lo);
        }
        __syncthreads();

        f16x8 fa[4], fb[4];
        #pragma unroll
        for (int i = 0; i < 4; ++i) {
            fa[i] = *(const f16x8*)&Pt[wr * 64 + i * 16 + lr][kq];
            fb[i] = *(const f16x8*)&Vt[wc * 64 + i * 16 + lr][kq];
        }
        #pragma unroll
        for (int i = 0; i < 4; ++i)
            #pragma unroll
            for (int j = 0; j < 4; ++j)
                acc[i][j] = MFMA16(fa[i], fb[j], acc[i][j]);
    }

    #pragma unroll
    for (int i = 0; i < 4; ++i) {
        #pragma unroll
        for (int j = 0; j < 4; ++j) {
            const int col = bn * 128 + wc * 64 + j * 16 + lr;
            #pragma unroll
            for (int r = 0; r < 4; ++r) {
                const int row = bm * 128 + wr * 64 + i * 16 + (lane >> 4) * 4 + r;
                out[((size_t)b * Ss + row) * Ee + col] = acc[i][j][r];
            }
        }
    }
}

// ================================================================ legacy path (fp32 fallback)
#define TQ 16
#define TK 256
#define EC 64
#define NCH (Ee/EC)
#define NT  (Ss/TK)

__global__ __launch_bounds__(256)
void qkv_gemm(const float* __restrict__ x,
              const float* __restrict__ Wq, const float* __restrict__ bq,
              const float* __restrict__ Wk, const float* __restrict__ bk,
              const float* __restrict__ Wv, const float* __restrict__ bv,
              float* __restrict__ oq, float* __restrict__ ok, float* __restrict__ ov)
{
    __shared__ float Xs[64][17];
    __shared__ float Ws[64][17];
    const int t = threadIdx.x;
    const int z = blockIdx.z;
    const float* __restrict__ W    = (z == 0) ? Wq : ((z == 1) ? Wk : Wv);
    const float* __restrict__ bias = (z == 0) ? bq : ((z == 1) ? bk : bv);
    float* __restrict__ out        = (z == 0) ? oq : ((z == 1) ? ok : ov);

    const int row0 = blockIdx.y << 6;
    const int col0 = blockIdx.x << 6;
    const int ti = t >> 4;
    const int tj = t & 15;
    const int lr = t >> 2;
    const int lc = (t & 3) << 2;

    float acc[4][4];
    #pragma unroll
    for (int i = 0; i < 4; ++i)
        #pragma unroll
        for (int j = 0; j < 4; ++j) acc[i][j] = 0.f;

    for (int e0 = 0; e0 < Ee; e0 += 16) {
        __syncthreads();
        {
            float4 xv = *(const float4*)&x[(row0 + lr)*Ee + e0 + lc];
            float4 wv = *(const float4*)&W[(col0 + lr)*Ee + e0 + lc];
            Xs[lr][lc]   = xv.x; Xs[lr][lc+1] = xv.y; Xs[lr][lc+2] = xv.z; Xs[lr][lc+3] = xv.w;
            Ws[lr][lc]   = wv.x; Ws[lr][lc+1] = wv.y; Ws[lr][lc+2] = wv.z; Ws[lr][lc+3] = wv.w;
        }
        __syncthreads();
        #pragma unroll
        for (int ee = 0; ee < 16; ++ee) {
            float xa[4], wb[4];
            #pragma unroll
            for (int i = 0; i < 4; ++i) xa[i] = Xs[(ti<<2)+i][ee];
            #pragma unroll
            for (int j = 0; j < 4; ++j) wb[j] = Ws[(tj<<2)+j][ee];
            #pragma unroll
            for (int i = 0; i < 4; ++i)
                #pragma unroll
                for (int j = 0; j < 4; ++j)
                    acc[i][j] = fmaf(xa[i], wb[j], acc[i][j]);
        }
    }

    const float4 b4 = *(const float4*)&bias[col0 + (tj<<2)];
    #pragma unroll
    for (int i = 0; i < 4; ++i) {
        float4 o;
        o.x = acc[i][0] + b4.x;
        o.y = acc[i][1] + b4.y;
        o.z = acc[i][2] + b4.z;
        o.w = acc[i][3] + b4.w;
        *(float4*)&out[(row0 + (ti<<2) + i)*Ee + col0 + (tj<<2)] = o;
    }
}

__global__ __launch_bounds__(256)
void flash_attn(const float* __restrict__ qsrc,
                const float* __restrict__ ksrc,
                const float* __restrict__ vsrc,
                float* __restrict__ out)
{
    __shared__ float qs[TQ][1028];
    __shared__ float kv[TK][68];
    __shared__ float ps[TQ][260];
    __shared__ float f_s[TQ];
    __shared__ float l_s[TQ];

    const int t = threadIdx.x;
    const int lane = t & 63;
    const int w = t >> 6;
    const int q0 = blockIdx.x * TQ;
    const int kb = (q0 / Ss) * Ss;

    {
        const int r = t >> 4;
        const int c0 = (t & 15) << 2;
        #pragma unroll
        for (int m = 0; m < 16; ++m) {
            float4 v4 = *(const float4*)&qsrc[(q0 + r)*Ee + c0 + (m << 6)];
            *(float4*)&qs[r][c0 + (m << 6)] = v4;
        }
    }

    float4 oacc[NCH];
    #pragma unroll
    for (int i = 0; i < NCH; ++i) oacc[i] = make_float4(0.f, 0.f, 0.f, 0.f);
    float m_reg[4], l_reg[4];
    #pragma unroll
    for (int i = 0; i < 4; ++i) { m_reg[i] = -INFINITY; l_reg[i] = 0.f; }

    const int ow = t >> 4;
    const int oc = (t & 15) << 2;

    for (int kt = 0; kt < NT; ++kt) {
        const int kr0 = kb + kt * TK;

        float sacc[4][4];
        #pragma unroll
        for (int i = 0; i < 4; ++i)
            #pragma unroll
            for (int j = 0; j < 4; ++j) sacc[i][j] = 0.f;

        for (int ec = 0; ec < NCH; ++ec) {
            __syncthreads();
            {
                const int rr = t >> 4;
                const int cc = (t & 15) << 2;
                #pragma unroll
                for (int m = 0; m < 16; ++m) {
                    float4 v4 = *(const float4*)&ksrc[(kr0 + rr + (m<<4))*Ee + ec*EC + cc];
                    *(float4*)&kv[rr + (m<<4)][cc] = v4;
                }
            }
            __syncthreads();
            #pragma unroll 4
            for (int ee = 0; ee < EC; ee += 4) {
                float4 q4[4];
                #pragma unroll
                for (int i = 0; i < 4; ++i)
                    q4[i] = *(const float4*)&qs[(w<<2)+i][ec*EC + ee];
                #pragma unroll
                for (int j = 0; j < 4; ++j) {
                    float4 k4 = *(const float4*)&kv[lane + (j<<6)][ee];
                    #pragma unroll
                    for (int i = 0; i < 4; ++i) {
                        sacc[i][j] = fmaf(q4[i].x, k4.x, sacc[i][j]);
                        sacc[i][j] = fmaf(q4[i].y, k4.y, sacc[i][j]);
                        sacc[i][j] = fmaf(q4[i].z, k4.z, sacc[i][j]);
                        sacc[i][j] = fmaf(q4[i].w, k4.w, sacc[i][j]);
                    }
                }
            }
        }

        float tmax[4];
        #pragma unroll
        for (int i = 0; i < 4; ++i)
            tmax[i] = fmaxf(fmaxf(sacc[i][0], sacc[i][1]), fmaxf(sacc[i][2], sacc[i][3]));
        #pragma unroll
        for (int off = 1; off < 64; off <<= 1) {
            #pragma unroll
            for (int i = 0; i < 4; ++i)
                tmax[i] = fmaxf(tmax[i], __shfl_xor(tmax[i], off, 64));
        }
        float rs[4], fi[4];
        #pragma unroll
        for (int i = 0; i < 4; ++i) {
            float mn = fmaxf(m_reg[i], tmax[i]);
            fi[i] = __expf(m_reg[i] - mn);
            m_reg[i] = mn;
            float r = 0.f;
            #pragma unroll
            for (int j = 0; j < 4; ++j) {
                float p = __expf(sacc[i][j] - mn);
                ps[(w<<2)+i][lane + (j<<6)] = p;
                r += p;
            }
            rs[i] = r;
        }
        #pragma unroll
        for (int off = 1; off < 64; off <<= 1) {
            #pragma unroll
            for (int i = 0; i < 4; ++i)
                rs[i] += __shfl_xor(rs[i], off, 64);
        }
        #pragma unroll
        for (int i = 0; i < 4; ++i)
            l_reg[i] = l_reg[i] * fi[i] + rs[i];
        if (lane == 0) {
            #pragma unroll
            for (int i = 0; i < 4; ++i) {
                f_s[(w<<2)+i] = fi[i];
                l_s[(w<<2)+i] = l_reg[i];
            }
        }
        __syncthreads();

        const float fown = f_s[ow];
        #pragma unroll
        for (int c4 = 0; c4 < NCH; ++c4) {
            oacc[c4].x *= fown; oacc[c4].y *= fown;
            oacc[c4].z *= fown; oacc[c4].w *= fown;
        }
        for (int pc = 0; pc < NCH; ++pc) {
            __syncthreads();
            {
                const int rr = t >> 4;
                const int cc = (t & 15) << 2;
                #pragma unroll
                for (int m = 0; m < 16; ++m) {
                    float4 v4 = *(const float4*)&vsrc[(kr0 + rr + (m<<4))*Ee + pc*EC + cc];
                    *(float4*)&kv[rr + (m<<4)][cc] = v4;
                }
            }
            __syncthreads();
            float4 acc = oacc[pc];
            #pragma unroll 4
            for (int tj0 = 0; tj0 < TK; tj0 += 4) {
                float4 p4 = *(const float4*)&ps[ow][tj0];
                float4 v0 = *(const float4*)&kv[tj0+0][oc];
                float4 v1 = *(const float4*)&kv[tj0+1][oc];
                float4 v2 = *(const float4*)&kv[tj0+2][oc];
                float4 v3 = *(const float4*)&kv[tj0+3][oc];
                acc.x = fmaf(p4.x, v0.x, acc.x); acc.y = fmaf(p4.x, v0.y, acc.y);
                acc.z = fmaf(p4.x, v0.z, acc.z); acc.w = fmaf(p4.x, v0.w, acc.w);
                acc.x = fmaf(p4.y, v1.x, acc.x); acc.y = fmaf(p4.y, v1.y, acc.y);
                acc.z = fmaf(p4.y, v1.z, acc.z); acc.w = fmaf(p4.y, v1.w, acc.w);
                acc.x = fmaf(p4.z, v2.x, acc.x); acc.y = fmaf(p4.z, v2.y, acc.y);
                acc.z = fmaf(p4.z, v2.z, acc.z); acc.w = fmaf(p4.z, v2.w, acc.w);
                acc.x = fmaf(p4.w, v3.x, acc.x); acc.y = fmaf(p4.w, v3.y, acc.y);
                acc.z = fmaf(p4.w, v3.z, acc.z); acc.w = fmaf(p4.w, v3.w, acc.w);
            }
            oacc[pc] = acc;
        }
    }

    __syncthreads();
    const float linv = 1.0f / l_s[ow];
    #pragma unroll
    for (int c4 = 0; c4 < NCH; ++c4) {
        float4 o = oacc[c4];
        o.x *= linv; o.y *= linv; o.z *= linv; o.w *= linv;
        *(float4*)&out[(q0 + ow)*Ee + oc + (c4 << 6)] = o;
    }
}

// ================================================================ launch
extern "C" void kernel_launch(void* const* d_in, const int* in_sizes, int n_in,
                              void* d_out, int out_size, void* d_ws, size_t ws_size,
                              hipStream_t stream)
{
    (void)in_sizes; (void)n_in; (void)out_size;
    const float* x  = (const float*)d_in[0];
    const float* Wq = (const float*)d_in[1];
    const float* bq = (const float*)d_in[2];
    const float* Wk = (const float*)d_in[3];
    const float* bk = (const float*)d_in[4];  (void)bk;  // cancels in softmax
    const float* Wv = (const float*)d_in[5];
    const float* bv = (const float*)d_in[6];
    float* out = (float*)d_out;

    const size_t S8 = 128 * MB, S4 = 64 * MB, S2 = 32 * MB;
    const size_t TAIL = 96 * MB + 16 * MB + MB;
    const size_t NEED8 = S8 + TAIL;
    const size_t NEED4 = S4 + TAIL;
    const size_t NEED2 = S2 + TAIL;

    if (ws_size >= NEED2) {
        const int nb = (ws_size >= NEED8) ? 8 : ((ws_size >= NEED4) ? 4 : 2);
        const size_t sb = (nb == 8) ? S8 : ((nb == 4) ? S4 : S2);
        char* base = (char*)d_ws;
        float* Sbuf = (float*)base;
        f16* xh   = (f16*)(base + sb);
        f16* qp   = (f16*)(base + sb + 32 * MB);
        f16* vT   = (f16*)(base + sb + 64 * MB);
        f16* Wvh  = (f16*)(base + sb + 96 * MB);
        f16* WqTh = (f16*)(base + sb + 98 * MB);
        f16* WqTl = (f16*)(base + sb + 100 * MB);
        f16* WkTh = (f16*)(base + sb + 102 * MB);
        f16* WkTl = (f16*)(base + sb + 104 * MB);
        f16* Mth  = (f16*)(base + sb + 106 * MB);
        f16* Mtl  = (f16*)(base + sb + 108 * MB);
        float* Mpart = (float*)(base + sb + 110 * MB);
        float* wbuf  = (float*)(base + sb + 126 * MB);

        split_xw<<<17408, 256, 0, stream>>>(x, Wv, xh, Wvh);
        transpose_split<<<dim3(16, 16, 2), 256, 0, stream>>>(Wq, Wk, WqTh, WqTl, WkTh, WkTl);
        compute_Mt<<<dim3(8, 8, 4), 256, 0, stream>>>(WkTh, WkTl, WqTh, WqTl, Mpart);
        reduce_Mt<<<1024, 256, 0, stream>>>(Mpart, Mth, Mtl);
        wker<<<4, 256, 0, stream>>>(Wk, bq, wbuf);
        proj3<<<512, 512, 0, stream>>>(xh, Mth, Mtl, Wvh, bv, wbuf, qp, vT);
        if (nb == 8) {
            score8<<<512, 512, 0, stream>>>(qp, xh, Sbuf, 0);
            softmax_rows<<<16384, 256, 0, stream>>>(Sbuf);
            pv256<<<256, 512, 0, stream>>>(Sbuf, vT, out);
        } else {
            for (int c = 0; c < 8 / nb; ++c) {
                score8<<<64 * nb, 512, 0, stream>>>(qp, xh, Sbuf, nb * c);
                softmax_rows<<<nb * 2048, 256, 0, stream>>>(Sbuf);
                pv_gemm<<<dim3(8, 16, nb), 256, 0, stream>>>(Sbuf, vT, out, nb * c);
            }
        }
    } else {
        // legacy fp32 path (needs 128 MB ws)
        float* kbuf = (float*)d_ws;
        float* vbuf2 = kbuf + (size_t)BSr * Ee;
        dim3 g1(Ee / 64, BSr / 64, 3);
        qkv_gemm<<<g1, 256, 0, stream>>>(x, Wq, bq, Wk, bk, Wv, bv, out, kbuf, vbuf2);
        flash_attn<<<dim3(BSr / TQ), 256, 0, stream>>>(out, kbuf, vbuf2, out);
    }
}

// Round 16
// 349.195 us; speedup vs baseline: 1.0899x; 1.0899x over previous
//
#include <hip/hip_runtime.h>
#include <math.h>

typedef _Float16 f16;
typedef _Float16 f16x8 __attribute__((ext_vector_type(8)));
typedef _Float16 f16x4 __attribute__((ext_vector_type(4)));
typedef float f32x4v __attribute__((ext_vector_type(4)));

#define Bb 8
#define Ss 2048
#define Ee 1024
#define BSr (Bb*Ss)
#define MB 1048576ull

// ---------------------------------------------------------------- helpers
__device__ __forceinline__ void gll16(const void* gp, void* lp) {
    __builtin_amdgcn_global_load_lds(
        (const __attribute__((address_space(1))) unsigned int*)gp,
        (__attribute__((address_space(3))) unsigned int*)lp,
        16, 0, 0);
}

#define MFMA16(a, b, c) __builtin_amdgcn_mfma_f32_16x16x32_f16((a), (b), (c), 0, 0, 0)
#define SBAR() asm volatile("s_barrier" ::: "memory")

// ================================================================ prep kernels
__global__ __launch_bounds__(256)
void split_xw(const float* __restrict__ x, const float* __restrict__ Wv,
              f16* __restrict__ xh, f16* __restrict__ Wvh)
{
    const int bid = blockIdx.x;
    const float* src; f16* dst; int i;
    if (bid < 16384) { src = x;  dst = xh;  i = (bid * 256 + threadIdx.x) * 4; }
    else             { src = Wv; dst = Wvh; i = ((bid - 16384) * 256 + threadIdx.x) * 4; }
    float4 v = *(const float4*)&src[i];
    f16x4 h4;
    h4[0] = (f16)v.x; h4[1] = (f16)v.y; h4[2] = (f16)v.z; h4[3] = (f16)v.w;
    *(f16x4*)&dst[i] = h4;
}

__global__ __launch_bounds__(256)
void transpose_split(const float* __restrict__ Wq, const float* __restrict__ Wk,
                     f16* __restrict__ WqTh, f16* __restrict__ WqTl,
                     f16* __restrict__ WkTh, f16* __restrict__ WkTl)
{
    __shared__ float ts[64][65];
    const int z = blockIdx.z;
    const float* W = z ? Wk : Wq;
    f16* Th = z ? WkTh : WqTh;
    f16* Tl = z ? WkTl : WqTl;
    const int e0 = blockIdx.x * 64, j0 = blockIdx.y * 64;
    const int t = threadIdx.x;
    {
        const int jj = t >> 2, c0 = (t & 3) * 16;
        #pragma unroll
        for (int m = 0; m < 4; ++m) {
            float4 v = *(const float4*)&W[(size_t)(j0 + jj) * Ee + e0 + c0 + m * 4];
            ts[jj][c0 + m*4 + 0] = v.x; ts[jj][c0 + m*4 + 1] = v.y;
            ts[jj][c0 + m*4 + 2] = v.z; ts[jj][c0 + m*4 + 3] = v.w;
        }
    }
    __syncthreads();
    {
        const int ee = t >> 2, jc0 = (t & 3) * 16;
        f16x8 h0, h1, l0, l1;
        #pragma unroll
        for (int m = 0; m < 16; ++m) {
            float val = ts[jc0 + m][ee];
            f16 hh = (f16)val; f16 ll = (f16)(val - (float)hh);
            if (m < 8) { h0[m] = hh; l0[m] = ll; }
            else       { h1[m-8] = hh; l1[m-8] = ll; }
        }
        size_t off = (size_t)(e0 + ee) * Ee + j0 + jc0;
        *(f16x8*)&Th[off]     = h0; *(f16x8*)&Th[off + 8] = h1;
        *(f16x8*)&Tl[off]     = l0; *(f16x8*)&Tl[off + 8] = l1;
    }
}

__global__ __launch_bounds__(256)
void compute_Mt(const f16* __restrict__ WkTh, const f16* __restrict__ WkTl,
                const f16* __restrict__ WqTh, const f16* __restrict__ WqTl,
                float* __restrict__ Mpart)
{
    __shared__ f16 Ah[128][32];
    __shared__ f16 Al[128][32];
    __shared__ f16 Bh[128][32];
    __shared__ f16 Bl[128][32];

    const int bn = blockIdx.x, bm = blockIdx.y, z = blockIdx.z;
    const int t = threadIdx.x;
    const int lane = t & 63;
    const int w = t >> 6;
    const int wr = w >> 1, wc = w & 1;
    const int lr = lane & 15;
    const int kq = (lane >> 4) << 3;
    const int rS = w * 32 + (lane >> 2);
    const int eS = (lane & 3) * 8;

    const f16* gAh = WkTh + ((size_t)(bm * 128 + rS)) * Ee + z * 256 + eS;
    const f16* gAl = WkTl + ((size_t)(bm * 128 + rS)) * Ee + z * 256 + eS;
    const f16* gBh = WqTh + ((size_t)(bn * 128 + rS)) * Ee + z * 256 + eS;
    const f16* gBl = WqTl + ((size_t)(bn * 128 + rS)) * Ee + z * 256 + eS;

    f32x4v acc[4][4];
    #pragma unroll
    for (int i = 0; i < 4; ++i)
        #pragma unroll
        for (int j = 0; j < 4; ++j) acc[i][j] = (f32x4v)0.f;

    for (int k0 = 0; k0 < 256; k0 += 32) {
        __syncthreads();
        #pragma unroll
        for (int c = 0; c < 2; ++c) {
            const size_t go = (size_t)c * 16 * Ee + k0;
            const int lo = w * 1024 + c * 512;
            gll16(gAh + go, &Ah[0][0] + lo);
            gll16(gAl + go, &Al[0][0] + lo);
            gll16(gBh + go, &Bh[0][0] + lo);
            gll16(gBl + go, &Bl[0][0] + lo);
        }
        __syncthreads();

        f16x8 fah[4], fal[4], fbh[4], fbl[4];
        #pragma unroll
        for (int i = 0; i < 4; ++i) {
            fah[i] = *(const f16x8*)&Ah[wr * 64 + i * 16 + lr][kq];
            fal[i] = *(const f16x8*)&Al[wr * 64 + i * 16 + lr][kq];
            fbh[i] = *(const f16x8*)&Bh[wc * 64 + i * 16 + lr][kq];
            fbl[i] = *(const f16x8*)&Bl[wc * 64 + i * 16 + lr][kq];
        }
        #pragma unroll
        for (int i = 0; i < 4; ++i)
            #pragma unroll
            for (int j = 0; j < 4; ++j) {
                acc[i][j] = MFMA16(fah[i], fbh[j], acc[i][j]);
                acc[i][j] = MFMA16(fah[i], fbl[j], acc[i][j]);
                acc[i][j] = MFMA16(fal[i], fbh[j], acc[i][j]);
            }
    }

    #pragma unroll
    for (int i = 0; i < 4; ++i) {
        #pragma unroll
        for (int j = 0; j < 4; ++j) {
            const int col = bn * 128 + wc * 64 + j * 16 + lr;
            #pragma unroll
            for (int r = 0; r < 4; ++r) {
                const int row = bm * 128 + wr * 64 + i * 16 + (lane >> 4) * 4 + r;
                Mpart[(size_t)z * MB + (size_t)row * Ee + col] = acc[i][j][r];
            }
        }
    }
}

__global__ __launch_bounds__(256)
void reduce_Mt(const float* __restrict__ Mpart, f16* __restrict__ Mth, f16* __restrict__ Mtl)
{
    const size_t i4 = ((size_t)blockIdx.x * 256 + threadIdx.x) * 4;
    float4 a = *(const float4*)&Mpart[i4];
    float4 b = *(const float4*)&Mpart[MB + i4];
    float4 c = *(const float4*)&Mpart[2 * MB + i4];
    float4 d = *(const float4*)&Mpart[3 * MB + i4];
    float s[4] = {a.x + b.x + c.x + d.x, a.y + b.y + c.y + d.y,
                  a.z + b.z + c.z + d.z, a.w + b.w + c.w + d.w};
    f16x4 h, l;
    #pragma unroll
    for (int m = 0; m < 4; ++m) { f16 hh = (f16)s[m]; h[m] = hh; l[m] = (f16)(s[m] - (float)hh); }
    *(f16x4*)&Mth[i4] = h;
    *(f16x4*)&Mtl[i4] = l;
}

// wpart[p][f] = sum_{j in seg p} Wk[j,f]*bq[j]. grid 32 (4 f-tiles x 8 j-segs).
__global__ __launch_bounds__(256)
void wker(const float* __restrict__ Wk, const float* __restrict__ bq,
          float* __restrict__ wpart)
{
    const int f = (blockIdx.x & 3) * 256 + threadIdx.x;
    const int p = blockIdx.x >> 2;
    float acc = 0.f;
    for (int j = p * 128; j < p * 128 + 128; ++j)
        acc += Wk[(size_t)j * Ee + f] * bq[j];
    wpart[p * Ee + f] = acc;
}

// wbuf[f] = sum_p wpart[p][f]. grid 4.
__global__ __launch_bounds__(256)
void wsum(const float* __restrict__ wpart, float* __restrict__ wbuf)
{
    const int f = blockIdx.x * 256 + threadIdx.x;
    float s = 0.f;
    #pragma unroll
    for (int p = 0; p < 8; ++p) s += wpart[p * Ee + f];
    wbuf[f] = s;
}

// ================================================================ round-12 K-loop (verified best)
template<bool DUAL>
__device__ __forceinline__ void kloop32(
    const f16* __restrict__ Ag, const int sA,
    const f16* __restrict__ Bhg, const f16* __restrict__ Blg, const int sB,
    const int NT, f16* __restrict__ lds,
    f32x4v acc[8][4], const int w, const int lane)
{
    constexpr int SETF = DUAL ? 24576 : 16384;
    const int wr = w >> 2, wc = w & 3;
    const int srcA = (w * 16 + (lane & 15)) * sA + (lane >> 4) * 8;
    const int srcB = (w * 16 + (lane & 15)) * sB + (lane >> 4) * 8;
    const int lrd = lane * 8;

#define STAGE8(t, s) do {                                                   \
        const int k0_ = (t) * 32;                                           \
        const f16* gA_ = Ag + k0_ + srcA;                                   \
        const f16* gB_ = Bhg + k0_ + srcB;                                  \
        f16* dA_ = lds + (s) * SETF + w * 512;                              \
        f16* dB_ = lds + (s) * SETF + 8192 + w * 512;                       \
        gll16(gA_,                       dA_);                              \
        gll16(gA_ + (size_t)8 * 16 * sA, dA_ + 8 * 512);                    \
        gll16(gB_,                       dB_);                              \
        gll16(gB_ + (size_t)8 * 16 * sB, dB_ + 8 * 512);                    \
        if (DUAL) {                                                         \
            const f16* gL_ = Blg + k0_ + srcB;                              \
            f16* dL_ = lds + (s) * SETF + 16384 + w * 512;                  \
            gll16(gL_,                       dL_);                          \
            gll16(gL_ + (size_t)8 * 16 * sB, dL_ + 8 * 512);                \
        }                                                                   \
    } while (0)

    STAGE8(0, 0);
    STAGE8(1, 1);
    if (DUAL) asm volatile("s_waitcnt vmcnt(6)" ::: "memory");
    else      asm volatile("s_waitcnt vmcnt(4)" ::: "memory");
    SBAR();

    for (int t = 0; t < NT; ++t) {
        const int s = t % 3;
        if (t + 2 < NT) STAGE8(t + 2, (t + 2) % 3);

        const f16* As = lds + s * SETF;
        const f16* Bh = As + 8192;
        const f16* Bl = As + 16384;
        f16x8 fa[8], fbh[4], fbl[4];
        #pragma unroll
        for (int i = 0; i < 8; ++i)
            fa[i] = *(const f16x8*)(As + (wr * 8 + i) * 512 + lrd);
        #pragma unroll
        for (int j = 0; j < 4; ++j)
            fbh[j] = *(const f16x8*)(Bh + (wc * 4 + j) * 512 + lrd);
        if (DUAL) {
            #pragma unroll
            for (int j = 0; j < 4; ++j)
                fbl[j] = *(const f16x8*)(Bl + (wc * 4 + j) * 512 + lrd);
        }
        #pragma unroll
        for (int j = 0; j < 4; ++j)
            #pragma unroll
            for (int i = 0; i < 8; ++i) {
                acc[i][j] = MFMA16(fa[i], fbh[j], acc[i][j]);
                if (DUAL)
                    acc[i][j] = MFMA16(fa[i], fbl[j], acc[i][j]);
            }

        if (t + 2 < NT) {
            if (DUAL) asm volatile("s_waitcnt vmcnt(6)" ::: "memory");
            else      asm volatile("s_waitcnt vmcnt(4)" ::: "memory");
        } else if (t + 1 < NT) {
            asm volatile("s_waitcnt vmcnt(0)" ::: "memory");
        }
        SBAR();
    }
#undef STAGE8
}

// ================================================================ proj3: q'' = xh*Mt^T + w (dual), v = xh*Wvh^T -> vT
__global__ __launch_bounds__(512, 2)
void proj3(const f16* __restrict__ xh,
           const f16* __restrict__ Mth, const f16* __restrict__ Mtl,
           const f16* __restrict__ Wvh, const float* __restrict__ bv,
           const float* __restrict__ wbuf,
           f16* __restrict__ qp, f16* __restrict__ vT)
{
    __shared__ f16 lds[73728];

    const int lin = blockIdx.x;
    const int l = (lin & 7) * 64 + (lin >> 3);
    const int zc = l & 7;
    const int by = l >> 3;
    const int z = zc >> 2;
    const int col0 = (zc & 3) * 256;
    const int row0 = by * 256;

    const int t = threadIdx.x;
    const int lane = t & 63;
    const int w = t >> 6;
    const int wr = w >> 2, wc = w & 3;

    f32x4v acc[8][4];
    #pragma unroll
    for (int i = 0; i < 8; ++i)
        #pragma unroll
        for (int j = 0; j < 4; ++j) acc[i][j] = (f32x4v)0.f;

    const f16* Ax = xh + (size_t)row0 * Ee;
    if (z == 0) {
        kloop32<true>(Ax, Ee, Mth + (size_t)col0 * Ee, Mtl + (size_t)col0 * Ee, Ee,
                      32, lds, acc, w, lane);
        #pragma unroll
        for (int i = 0; i < 8; ++i) {
            #pragma unroll
            for (int j = 0; j < 4; ++j) {
                const int col = col0 + wc * 64 + j * 16 + (lane & 15);
                const float b = wbuf[col];   // folds score's per-column +v_b
                #pragma unroll
                for (int r = 0; r < 4; ++r) {
                    const int row = row0 + wr * 128 + i * 16 + (lane >> 4) * 4 + r;
                    qp[(size_t)row * Ee + col] = (f16)(acc[i][j][r] + b);
                }
            }
        }
    } else {
        kloop32<false>(Ax, Ee, Wvh + (size_t)col0 * Ee, Wvh + (size_t)col0 * Ee, Ee,
                       32, lds, acc, w, lane);
        #pragma unroll
        for (int i = 0; i < 8; ++i) {
            #pragma unroll
            for (int j = 0; j < 4; ++j) {
                const int e = col0 + wc * 64 + j * 16 + (lane & 15);
                const float b = bv[e];
                const int srow = row0 + wr * 128 + i * 16 + (lane >> 4) * 4;
                const int bb = srow >> 11;
                const int s = srow & 2047;
                f16x4 pk;
                #pragma unroll
                for (int r = 0; r < 4; ++r) pk[r] = (f16)(acc[i][j][r] + b);
                *(f16x4*)&vT[((size_t)bb * Ee + e) * Ss + s] = pk;
            }
        }
    }
}

// ================================================================ scores: S = q'' * xh^T
__global__ __launch_bounds__(512, 2)
void score8(const f16* __restrict__ qp, const f16* __restrict__ xh,
            float* __restrict__ Sbuf, int batch0)
{
    __shared__ f16 lds[49152];

    const int lin = blockIdx.x;
    const int cpx = gridDim.x >> 3;
    const int l = (lin & 7) * cpx + (lin >> 3);
    const int bn = l & 7;
    const int bm = (l >> 3) & 7;
    const int zb = l >> 6;
    const int b = batch0 + zb;

    const int t = threadIdx.x;
    const int lane = t & 63;
    const int w = t >> 6;
    const int wr = w >> 2, wc = w & 3;

    const f16* Aq = qp + ((size_t)b * Ss + bm * 256) * Ee;
    const f16* Bk = xh + ((size_t)b * Ss + bn * 256) * Ee;

    f32x4v acc[8][4];
    #pragma unroll
    for (int i = 0; i < 8; ++i)
        #pragma unroll
        for (int j = 0; j < 4; ++j) acc[i][j] = (f32x4v)0.f;

    kloop32<false>(Aq, Ee, Bk, Bk, Ee, 32, lds, acc, w, lane);

    #pragma unroll
    for (int i = 0; i < 8; ++i) {
        #pragma unroll
        for (int j = 0; j < 4; ++j) {
            const int col = bn * 256 + wc * 64 + j * 16 + (lane & 15);
            #pragma unroll
            for (int r = 0; r < 4; ++r) {
                const int row = zb * Ss + bm * 256 + wr * 128 + i * 16 + (lane >> 4) * 4 + r;
                Sbuf[(size_t)row * 2048 + col] = acc[i][j][r];
            }
        }
    }
}

// ================================================================ row softmax
__global__ __launch_bounds__(256)
void softmax_rows(float* __restrict__ Sbuf)
{
    __shared__ float red[8];
    const int t = threadIdx.x;
    const int w = t >> 6;
    float* Srow = Sbuf + (size_t)blockIdx.x * 2048;

    float4 a = *(const float4*)&Srow[t * 8];
    float4 c = *(const float4*)&Srow[t * 8 + 4];
    float v[8] = {a.x, a.y, a.z, a.w, c.x, c.y, c.z, c.w};

    float m = v[0];
    #pragma unroll
    for (int i = 1; i < 8; ++i) m = fmaxf(m, v[i]);
    #pragma unroll
    for (int off = 1; off < 64; off <<= 1) m = fmaxf(m, __shfl_xor(m, off, 64));
    if ((t & 63) == 0) red[w] = m;
    __syncthreads();
    m = fmaxf(fmaxf(red[0], red[1]), fmaxf(red[2], red[3]));

    float e[8], s = 0.f;
    #pragma unroll
    for (int i = 0; i < 8; ++i) { e[i] = __expf(v[i] - m); s += e[i]; }
    #pragma unroll
    for (int off = 1; off < 64; off <<= 1) s += __shfl_xor(s, off, 64);
    if ((t & 63) == 0) red[4 + w] = s;
    __syncthreads();
    s = red[4] + red[5] + red[6] + red[7];

    const float inv = 1.0f / s;
    f16x8 pk;
    #pragma unroll
    for (int i = 0; i < 8; ++i) pk[i] = (f16)(e[i] * inv);
    *(f16x8*)(((f16*)Srow) + t * 8) = pk;
}

// ================================================================ pv256: O = P*v, all 8 batches. grid 256.
__global__ __launch_bounds__(512, 2)
void pv256(const float* __restrict__ Sbuf, const f16* __restrict__ vT,
           float* __restrict__ out)
{
    __shared__ f16 lds[49152];

    const int lin = blockIdx.x;
    const int l = (lin & 7) * 32 + (lin >> 3);
    const int bn = l & 3;
    const int bm = (l >> 2) & 7;
    const int b  = l >> 5;

    const int t = threadIdx.x;
    const int lane = t & 63;
    const int w = t >> 6;
    const int wr = w >> 2, wc = w & 3;

    const f16* gA = (const f16*)Sbuf + ((size_t)(b * Ss + bm * 256)) * 4096;
    const f16* gB = vT + ((size_t)b * Ee + bn * 256) * Ss;

    f32x4v acc[8][4];
    #pragma unroll
    for (int i = 0; i < 8; ++i)
        #pragma unroll
        for (int j = 0; j < 4; ++j) acc[i][j] = (f32x4v)0.f;

    kloop32<false>(gA, 4096, gB, gB, Ss, 64, lds, acc, w, lane);

    #pragma unroll
    for (int i = 0; i < 8; ++i) {
        #pragma unroll
        for (int j = 0; j < 4; ++j) {
            const int col = bn * 256 + wc * 64 + j * 16 + (lane & 15);
            #pragma unroll
            for (int r = 0; r < 4; ++r) {
                const int row = bm * 256 + wr * 128 + i * 16 + (lane >> 4) * 4 + r;
                out[((size_t)b * Ss + row) * Ee + col] = acc[i][j][r];
            }
        }
    }
}

// ================================================================ pv_gemm (128^2 fallback for nb<8)
__global__ __launch_bounds__(256)
void pv_gemm(const float* __restrict__ Sbuf, const f16* __restrict__ vT,
             float* __restrict__ out, int batch0)
{
    __shared__ f16 Pt[128][32];
    __shared__ f16 Vt[128][32];

    const int zb = blockIdx.z;
    const int b = batch0 + zb;
    const int bm = blockIdx.y;
    const int bn = blockIdx.x;

    const int t = threadIdx.x;
    const int lane = t & 63;
    const int w = t >> 6;
    const int wr = w >> 1, wc = w & 1;
    const int lr = lane & 15;
    const int kq = (lane >> 4) << 3;

    const int rS = w * 32 + (lane >> 2);
    const int eS = (lane & 3) * 8;

    const f16* Pbase = (const f16*)Sbuf;
    const f16* gA = Pbase + ((size_t)(zb * Ss + bm * 128 + rS)) * 4096 + eS;
    const f16* gB = vT + ((size_t)b * Ee + bn * 128 + rS) * Ss + eS;

    f32x4v acc[4][4];
    #pragma unroll
    for (int i = 0; i < 4; ++i)
        #pragma unroll
        for (int j = 0; j < 4; ++j) acc[i][j] = (f32x4v)0.f;

    for (int k0 = 0; k0 < Ss; k0 += 32) {
        __syncthreads();
        #pragma unroll
        for (int c = 0; c < 2; ++c) {
            const int lo = w * 1024 + c * 512;
            gll16(gA + (size_t)c * 16 * 4096 + k0, &Pt[0][0] + lo);
            gll16(gB + (size_t)c * 16 * Ss + k0,   &Vt[0][0] + lo);
        }
        __syncthreads();

        f16x8 fa[4], fb[4];
        #pragma unroll
        for (int i = 0; i < 4; ++i) {
            fa[i] = *(const f16x8*)&Pt[wr * 64 + i * 16 + lr][kq];
            fb[i] = *(const f16x8*)&Vt[wc * 64 + i * 16 + lr][kq];
        }
        #pragma unroll
        for (int i = 0; i < 4; ++i)
            #pragma unroll
            for (int j = 0; j < 4; ++j)
                acc[i][j] = MFMA16(fa[i], fb[j], acc[i][j]);
    }

    #pragma unroll
    for (int i = 0; i < 4; ++i) {
        #pragma unroll
        for (int j = 0; j < 4; ++j) {
            const int col = bn * 128 + wc * 64 + j * 16 + lr;
            #pragma unroll
            for (int r = 0; r < 4; ++r) {
                const int row = bm * 128 + wr * 64 + i * 16 + (lane >> 4) * 4 + r;
                out[((size_t)b * Ss + row) * Ee + col] = acc[i][j][r];
            }
        }
    }
}

// ================================================================ legacy path (fp32 fallback)
#define TQ 16
#define TK 256
#define EC 64
#define NCH (Ee/EC)
#define NT  (Ss/TK)

__global__ __launch_bounds__(256)
void qkv_gemm(const float* __restrict__ x,
              const float* __restrict__ Wq, const float* __restrict__ bq,
              const float* __restrict__ Wk, const float* __restrict__ bk,
              const float* __restrict__ Wv, const float* __restrict__ bv,
              float* __restrict__ oq, float* __restrict__ ok, float* __restrict__ ov)
{
    __shared__ float Xs[64][17];
    __shared__ float Ws[64][17];
    const int t = threadIdx.x;
    const int z = blockIdx.z;
    const float* __restrict__ W    = (z == 0) ? Wq : ((z == 1) ? Wk : Wv);
    const float* __restrict__ bias = (z == 0) ? bq : ((z == 1) ? bk : bv);
    float* __restrict__ out        = (z == 0) ? oq : ((z == 1) ? ok : ov);

    const int row0 = blockIdx.y << 6;
    const int col0 = blockIdx.x << 6;
    const int ti = t >> 4;
    const int tj = t & 15;
    const int lr = t >> 2;
    const int lc = (t & 3) << 2;

    float acc[4][4];
    #pragma unroll
    for (int i = 0; i < 4; ++i)
        #pragma unroll
        for (int j = 0; j < 4; ++j) acc[i][j] = 0.f;

    for (int e0 = 0; e0 < Ee; e0 += 16) {
        __syncthreads();
        {
            float4 xv = *(const float4*)&x[(row0 + lr)*Ee + e0 + lc];
            float4 wv = *(const float4*)&W[(col0 + lr)*Ee + e0 + lc];
            Xs[lr][lc]   = xv.x; Xs[lr][lc+1] = xv.y; Xs[lr][lc+2] = xv.z; Xs[lr][lc+3] = xv.w;
            Ws[lr][lc]   = wv.x; Ws[lr][lc+1] = wv.y; Ws[lr][lc+2] = wv.z; Ws[lr][lc+3] = wv.w;
        }
        __syncthreads();
        #pragma unroll
        for (int ee = 0; ee < 16; ++ee) {
            float xa[4], wb[4];
            #pragma unroll
            for (int i = 0; i < 4; ++i) xa[i] = Xs[(ti<<2)+i][ee];
            #pragma unroll
            for (int j = 0; j < 4; ++j) wb[j] = Ws[(tj<<2)+j][ee];
            #pragma unroll
            for (int i = 0; i < 4; ++i)
                #pragma unroll
                for (int j = 0; j < 4; ++j)
                    acc[i][j] = fmaf(xa[i], wb[j], acc[i][j]);
        }
    }

    const float4 b4 = *(const float4*)&bias[col0 + (tj<<2)];
    #pragma unroll
    for (int i = 0; i < 4; ++i) {
        float4 o;
        o.x = acc[i][0] + b4.x;
        o.y = acc[i][1] + b4.y;
        o.z = acc[i][2] + b4.z;
        o.w = acc[i][3] + b4.w;
        *(float4*)&out[(row0 + (ti<<2) + i)*Ee + col0 + (tj<<2)] = o;
    }
}

__global__ __launch_bounds__(256)
void flash_attn(const float* __restrict__ qsrc,
                const float* __restrict__ ksrc,
                const float* __restrict__ vsrc,
                float* __restrict__ out)
{
    __shared__ float qs[TQ][1028];
    __shared__ float kv[TK][68];
    __shared__ float ps[TQ][260];
    __shared__ float f_s[TQ];
    __shared__ float l_s[TQ];

    const int t = threadIdx.x;
    const int lane = t & 63;
    const int w = t >> 6;
    const int q0 = blockIdx.x * TQ;
    const int kb = (q0 / Ss) * Ss;

    {
        const int r = t >> 4;
        const int c0 = (t & 15) << 2;
        #pragma unroll
        for (int m = 0; m < 16; ++m) {
            float4 v4 = *(const float4*)&qsrc[(q0 + r)*Ee + c0 + (m << 6)];
            *(float4*)&qs[r][c0 + (m << 6)] = v4;
        }
    }

    float4 oacc[NCH];
    #pragma unroll
    for (int i = 0; i < NCH; ++i) oacc[i] = make_float4(0.f, 0.f, 0.f, 0.f);
    float m_reg[4], l_reg[4];
    #pragma unroll
    for (int i = 0; i < 4; ++i) { m_reg[i] = -INFINITY; l_reg[i] = 0.f; }

    const int ow = t >> 4;
    const int oc = (t & 15) << 2;

    for (int kt = 0; kt < NT; ++kt) {
        const int kr0 = kb + kt * TK;

        float sacc[4][4];
        #pragma unroll
        for (int i = 0; i < 4; ++i)
            #pragma unroll
            for (int j = 0; j < 4; ++j) sacc[i][j] = 0.f;

        for (int ec = 0; ec < NCH; ++ec) {
            __syncthreads();
            {
                const int rr = t >> 4;
                const int cc = (t & 15) << 2;
                #pragma unroll
                for (int m = 0; m < 16; ++m) {
                    float4 v4 = *(const float4*)&ksrc[(kr0 + rr + (m<<4))*Ee + ec*EC + cc];
                    *(float4*)&kv[rr + (m<<4)][cc] = v4;
                }
            }
            __syncthreads();
            #pragma unroll 4
            for (int ee = 0; ee < EC; ee += 4) {
                float4 q4[4];
                #pragma unroll
                for (int i = 0; i < 4; ++i)
                    q4[i] = *(const float4*)&qs[(w<<2)+i][ec*EC + ee];
                #pragma unroll
                for (int j = 0; j < 4; ++j) {
                    float4 k4 = *(const float4*)&kv[lane + (j<<6)][ee];
                    #pragma unroll
                    for (int i = 0; i < 4; ++i) {
                        sacc[i][j] = fmaf(q4[i].x, k4.x, sacc[i][j]);
                        sacc[i][j] = fmaf(q4[i].y, k4.y, sacc[i][j]);
                        sacc[i][j] = fmaf(q4[i].z, k4.z, sacc[i][j]);
                        sacc[i][j] = fmaf(q4[i].w, k4.w, sacc[i][j]);
                    }
                }
            }
        }

        float tmax[4];
        #pragma unroll
        for (int i = 0; i < 4; ++i)
            tmax[i] = fmaxf(fmaxf(sacc[i][0], sacc[i][1]), fmaxf(sacc[i][2], sacc[i][3]));
        #pragma unroll
        for (int off = 1; off < 64; off <<= 1) {
            #pragma unroll
            for (int i = 0; i < 4; ++i)
                tmax[i] = fmaxf(tmax[i], __shfl_xor(tmax[i], off, 64));
        }
        float rs[4], fi[4];
        #pragma unroll
        for (int i = 0; i < 4; ++i) {
            float mn = fmaxf(m_reg[i], tmax[i]);
            fi[i] = __expf(m_reg[i] - mn);
            m_reg[i] = mn;
            float r = 0.f;
            #pragma unroll
            for (int j = 0; j < 4; ++j) {
                float p = __expf(sacc[i][j] - mn);
                ps[(w<<2)+i][lane + (j<<6)] = p;
                r += p;
            }
            rs[i] = r;
        }
        #pragma unroll
        for (int off = 1; off < 64; off <<= 1) {
            #pragma unroll
            for (int i = 0; i < 4; ++i)
                rs[i] += __shfl_xor(rs[i], off, 64);
        }
        #pragma unroll
        for (int i = 0; i < 4; ++i)
            l_reg[i] = l_reg[i] * fi[i] + rs[i];
        if (lane == 0) {
            #pragma unroll
            for (int i = 0; i < 4; ++i) {
                f_s[(w<<2)+i] = fi[i];
                l_s[(w<<2)+i] = l_reg[i];
            }
        }
        __syncthreads();

        const float fown = f_s[ow];
        #pragma unroll
        for (int c4 = 0; c4 < NCH; ++c4) {
            oacc[c4].x *= fown; oacc[c4].y *= fown;
            oacc[c4].z *= fown; oacc[c4].w *= fown;
        }
        for (int pc = 0; pc < NCH; ++pc) {
            __syncthreads();
            {
                const int rr = t >> 4;
                const int cc = (t & 15) << 2;
                #pragma unroll
                for (int m = 0; m < 16; ++m) {
                    float4 v4 = *(const float4*)&vsrc[(kr0 + rr + (m<<4))*Ee + pc*EC + cc];
                    *(float4*)&kv[rr + (m<<4)][cc] = v4;
                }
            }
            __syncthreads();
            float4 acc = oacc[pc];
            #pragma unroll 4
            for (int tj0 = 0; tj0 < TK; tj0 += 4) {
                float4 p4 = *(const float4*)&ps[ow][tj0];
                float4 v0 = *(const float4*)&kv[tj0+0][oc];
                float4 v1 = *(const float4*)&kv[tj0+1][oc];
                float4 v2 = *(const float4*)&kv[tj0+2][oc];
                float4 v3 = *(const float4*)&kv[tj0+3][oc];
                acc.x = fmaf(p4.x, v0.x, acc.x); acc.y = fmaf(p4.x, v0.y, acc.y);
                acc.z = fmaf(p4.x, v0.z, acc.z); acc.w = fmaf(p4.x, v0.w, acc.w);
                acc.x = fmaf(p4.y, v1.x, acc.x); acc.y = fmaf(p4.y, v1.y, acc.y);
                acc.z = fmaf(p4.y, v1.z, acc.z); acc.w = fmaf(p4.y, v1.w, acc.w);
                acc.x = fmaf(p4.z, v2.x, acc.x); acc.y = fmaf(p4.z, v2.y, acc.y);
                acc.z = fmaf(p4.z, v2.z, acc.z); acc.w = fmaf(p4.z, v2.w, acc.w);
                acc.x = fmaf(p4.w, v3.x, acc.x); acc.y = fmaf(p4.w, v3.y, acc.y);
                acc.z = fmaf(p4.w, v3.z, acc.z); acc.w = fmaf(p4.w, v3.w, acc.w);
            }
            oacc[pc] = acc;
        }
    }

    __syncthreads();
    const float linv = 1.0f / l_s[ow];
    #pragma unroll
    for (int c4 = 0; c4 < NCH; ++c4) {
        float4 o = oacc[c4];
        o.x *= linv; o.y *= linv; o.z *= linv; o.w *= linv;
        *(float4*)&out[(q0 + ow)*Ee + oc + (c4 << 6)] = o;
    }
}

// ================================================================ launch
extern "C" void kernel_launch(void* const* d_in, const int* in_sizes, int n_in,
                              void* d_out, int out_size, void* d_ws, size_t ws_size,
                              hipStream_t stream)
{
    (void)in_sizes; (void)n_in; (void)out_size;
    const float* x  = (const float*)d_in[0];
    const float* Wq = (const float*)d_in[1];
    const float* bq = (const float*)d_in[2];
    const float* Wk = (const float*)d_in[3];
    const float* bk = (const float*)d_in[4];  (void)bk;  // cancels in softmax
    const float* Wv = (const float*)d_in[5];
    const float* bv = (const float*)d_in[6];
    float* out = (float*)d_out;

    const size_t S8 = 128 * MB, S4 = 64 * MB, S2 = 32 * MB;
    const size_t TAIL = 96 * MB + 16 * MB + MB;
    const size_t NEED8 = S8 + TAIL;
    const size_t NEED4 = S4 + TAIL;
    const size_t NEED2 = S2 + TAIL;

    if (ws_size >= NEED2) {
        const int nb = (ws_size >= NEED8) ? 8 : ((ws_size >= NEED4) ? 4 : 2);
        const size_t sb = (nb == 8) ? S8 : ((nb == 4) ? S4 : S2);
        char* base = (char*)d_ws;
        float* Sbuf = (float*)base;
        f16* xh   = (f16*)(base + sb);
        f16* qp   = (f16*)(base + sb + 32 * MB);
        f16* vT   = (f16*)(base + sb + 64 * MB);
        f16* Wvh  = (f16*)(base + sb + 96 * MB);
        f16* WqTh = (f16*)(base + sb + 98 * MB);
        f16* WqTl = (f16*)(base + sb + 100 * MB);
        f16* WkTh = (f16*)(base + sb + 102 * MB);
        f16* WkTl = (f16*)(base + sb + 104 * MB);
        f16* Mth  = (f16*)(base + sb + 106 * MB);
        f16* Mtl  = (f16*)(base + sb + 108 * MB);
        float* Mpart = (float*)(base + sb + 110 * MB);
        float* wpart = (float*)(base + sb + 126 * MB);
        float* wbuf  = (float*)(base + sb + 126 * MB + 65536);

        split_xw<<<17408, 256, 0, stream>>>(x, Wv, xh, Wvh);
        transpose_split<<<dim3(16, 16, 2), 256, 0, stream>>>(Wq, Wk, WqTh, WqTl, WkTh, WkTl);
        compute_Mt<<<dim3(8, 8, 4), 256, 0, stream>>>(WkTh, WkTl, WqTh, WqTl, Mpart);
        reduce_Mt<<<1024, 256, 0, stream>>>(Mpart, Mth, Mtl);
        wker<<<32, 256, 0, stream>>>(Wk, bq, wpart);
        wsum<<<4, 256, 0, stream>>>(wpart, wbuf);
        proj3<<<512, 512, 0, stream>>>(xh, Mth, Mtl, Wvh, bv, wbuf, qp, vT);
        if (nb == 8) {
            score8<<<512, 512, 0, stream>>>(qp, xh, Sbuf, 0);
            softmax_rows<<<16384, 256, 0, stream>>>(Sbuf);
            pv256<<<256, 512, 0, stream>>>(Sbuf, vT, out);
        } else {
            for (int c = 0; c < 8 / nb; ++c) {
                score8<<<64 * nb, 512, 0, stream>>>(qp, xh, Sbuf, nb * c);
                softmax_rows<<<nb * 2048, 256, 0, stream>>>(Sbuf);
                pv_gemm<<<dim3(8, 16, nb), 256, 0, stream>>>(Sbuf, vT, out, nb * c);
            }
        }
    } else {
        // legacy fp32 path (needs 128 MB ws)
        float* kbuf = (float*)d_ws;
        float* vbuf2 = kbuf + (size_t)BSr * Ee;
        dim3 g1(Ee / 64, BSr / 64, 3);
        qkv_gemm<<<g1, 256, 0, stream>>>(x, Wq, bq, Wk, bk, Wv, bv, out, kbuf, vbuf2);
        flash_attn<<<dim3(BSr / TQ), 256, 0, stream>>>(out, kbuf, vbuf2, out);
    }
}